// Round 15
// baseline (90.112 us; speedup 1.0000x reference)
//
#include <hip/hip_runtime.h>

// RoiPooling (crop_and_resize, bilinear): x (1,128,128,256) f32 NHWC,
// rois (4000,4) f32 [y1,x1,y2,x2] in [0,1] -> out (4000,7,7,256) f32.
//
// R15: bucket-LDS pool. Bucket = (y0, x0>>3) -> 2048 buckets; one bucket
// per block; block stages rows {y0,y0+1} x 9 cols (18KB LDS, 8 blocks/CU)
// and serves its ~96 cells' gathers from LDS. L2 reads 784MB -> ~40MB.
// Sort: 3 dispatches, CAP-slot (no prefix): zero(32k ints), bin (pair-
// parallel, LDS hist+rank, merge ~65 atomics per padded line), pool.
// Overflow spill (CAP=512 exceeded) drained by 8 extra blocks (expected 0).
// R13's failure causes removed: 34KB->18KB LDS, 5->3 dispatches, no
// 1024-prefix, no static 3-block split, pair-parallel bin.

typedef float v4f __attribute__((ext_vector_type(4)));

constexpr int H = 128, W = 128, C = 256;
constexpr int PH = 7, PW = 7;
constexpr int NROI = 4000;
constexpr int NPAIR = NROI * PH;                 // 28000
constexpr int NCELL = NROI * PH * PW;            // 196000
constexpr int NB = 128 * 16;                     // (y0, x0>>3) buckets
constexpr int CAP = 512;                         // slots per bucket
constexpr int CS = 16;                           // ints; 64B per counter
constexpr int PAIR_BLOCKS = (NPAIR + 255) / 256; // 110
constexpr int DRAIN_BLOCKS = 8;
constexpr int POOL_BLOCKS = NB + DRAIN_BLOCKS;   // 2056
// ws: gcnt[NB*CS] | ocnt[CS] | list[NB*CAP] | olist[NCELL]
constexpr size_t WS_INTS = (size_t)NB * CS + CS + (size_t)NB * CAP + NCELL;

__global__ __launch_bounds__(256) void zero_counts(int* p) {
    const int n = NB * CS + CS;
    const int i = blockIdx.x * 256 + threadIdx.x;
    for (int j = i; j < n; j += 32 * 256) p[j] = 0;
}

// Shared geometry: MUST be bit-identical in bin and pool so buckets match.
__device__ __forceinline__ float ys_of(float y1, float y2, int iy) {
    return y1 * (float)(H - 1) + (float)iy * ((y2 - y1) * (float)(H - 1) / (float)(PH - 1));
}
__device__ __forceinline__ float xs_of(float x1, float x2, int ix) {
    return x1 * (float)(W - 1) + (float)ix * ((x2 - x1) * (float)(W - 1) / (float)(PW - 1));
}

__global__ __launch_bounds__(256) void bin_cells(const float* __restrict__ rois,
                                                 int* __restrict__ gcnt,
                                                 int* __restrict__ ocnt,
                                                 int* __restrict__ list,
                                                 int* __restrict__ olist)
{
    __shared__ int lh[NB];                       // 8KB
    for (int i = threadIdx.x; i < NB; i += 256) lh[i] = 0;
    __syncthreads();

    const int pr = blockIdx.x * 256 + threadIdx.x;
    const bool act = pr < NPAIR;
    int keys[PW], ranks[PW];
    if (act) {
        const int r  = pr / PH;
        const int iy = pr - r * PH;
        const float y1 = rois[r * 4 + 0];
        const float x1 = rois[r * 4 + 1];
        const float y2 = rois[r * 4 + 2];
        const float x2 = rois[r * 4 + 3];
        int y0 = (int)floorf(ys_of(y1, y2, iy));
        y0 = min(max(y0, 0), H - 1);
        const int ybase = y0 << 4;
#pragma unroll
        for (int ix = 0; ix < PW; ++ix) {
            int x0 = (int)floorf(xs_of(x1, x2, ix));
            x0 = min(max(x0, 0), W - 1);
            keys[ix] = ybase | (x0 >> 3);
            ranks[ix] = atomicAdd(&lh[keys[ix]], 1);
        }
    }
    __syncthreads();
    // Merge: claim global slot ranges; overwrite lh with the block's base.
    for (int i = threadIdx.x; i < NB; i += 256) {
        const int n = lh[i];
        lh[i] = n ? atomicAdd(&gcnt[i * CS], n) : 0;
    }
    __syncthreads();
    if (act) {
#pragma unroll
        for (int ix = 0; ix < PW; ++ix) {
            const int idx = lh[keys[ix]] + ranks[ix];
            const int cell = (pr << 3) | ix;
            if (idx < CAP) list[keys[ix] * CAP + idx] = cell;
            else           olist[atomicAdd(ocnt, 1)] = cell;
        }
    }
}

// Full reference math for one cell; gathers via callback-free switch:
// mode 0 = global reads, mode 1 = LDS reads (lds base given).
__device__ __forceinline__ void cell_compute_store(
    const float* __restrict__ rois, float* __restrict__ out, int packed,
    const float* src0, const float* src1,   // row pointers (global or LDS)
    int colstride, int colbase, int c4, bool fromLds, const float* __restrict__ xg)
{
    const int pr = packed >> 3;
    const int ix = packed & 7;
    const int r  = pr / PH;
    const int iy = pr - r * PH;

    const float y1 = rois[r * 4 + 0];
    const float x1 = rois[r * 4 + 1];
    const float y2 = rois[r * 4 + 2];
    const float x2 = rois[r * 4 + 3];

    const float ys = ys_of(y1, y2, iy);
    const float xs = xs_of(x1, x2, ix);
    const float y0f = floorf(ys);
    const float x0f = floorf(xs);
    const float wy = ys - y0f;
    const float wx = xs - x0f;

    int y0  = (int)y0f; y0  = min(max(y0, 0), H - 1);
    int y1i = min(y0 + 1, H - 1);
    int x0  = (int)x0f; x0  = min(max(x0, 0), W - 1);
    int x1c = min(x0 + 1, W - 1);

    const bool valid = (ys >= 0.0f) & (ys <= (float)(H - 1)) &
                       (xs >= 0.0f) & (xs <= (float)(W - 1));

    v4f a, b, c, d;
    if (fromLds) {
        const int lx0 = x0  - colbase;
        const int lx1 = x1c - colbase;
        const int ry1 = y1i - y0;
        const float* r0 = src0;
        const float* r1 = ry1 ? src1 : src0;
        a = *(const v4f*)(r0 + lx0 * colstride + c4);
        b = *(const v4f*)(r0 + lx1 * colstride + c4);
        c = *(const v4f*)(r1 + lx0 * colstride + c4);
        d = *(const v4f*)(r1 + lx1 * colstride + c4);
    } else {
        const float* r0 = xg + (unsigned)y0  * (W * C);
        const float* r1 = xg + (unsigned)y1i * (W * C);
        a = *(const v4f*)(r0 + (unsigned)x0  * C + c4);
        b = *(const v4f*)(r0 + (unsigned)x1c * C + c4);
        c = *(const v4f*)(r1 + (unsigned)x0  * C + c4);
        d = *(const v4f*)(r1 + (unsigned)x1c * C + c4);
    }

    const v4f top = a * (1.0f - wx) + b * wx;
    const v4f bot = c * (1.0f - wx) + d * wx;
    v4f res = top * (1.0f - wy) + bot * wy;
    if (!valid) res = (v4f)0.0f;
    __builtin_nontemporal_store(res, (v4f*)(out + (unsigned)(r * 49 + iy * 7 + ix) * C + c4));
}

__global__ __launch_bounds__(256) void roi_pool_bucket(
    const float* __restrict__ x, const float* __restrict__ rois,
    float* __restrict__ out, const int* __restrict__ gcnt,
    const int* __restrict__ list, const int* __restrict__ ocnt,
    const int* __restrict__ olist)
{
    __shared__ float lds[2][9][C];               // 18KB
    const int wave = threadIdx.x >> 6;
    const int lane = threadIdx.x & 63;
    const int c4 = lane * 4;

    if (blockIdx.x < NB) {
        // XCD-affine: XCD j owns buckets j*256..j*256+255 (rows 16j..16j+15).
        const int b = (blockIdx.x & 7) * 256 + (blockIdx.x >> 3);
        const int n = min(gcnt[b * CS], CAP);
        if (n == 0) return;
        const int y0s = b >> 4;
        const int colbase = (b & 15) << 3;

        // Stage 2 rows x 9 cols (1KB each chunk).
        for (int chunk = wave; chunk < 18; chunk += 4) {
            const int row = chunk < 9 ? 0 : 1;
            const int col = chunk - row * 9;
            const int gy = min(y0s + row, H - 1);
            const int gx = min(colbase + col, W - 1);
            const v4f v = *(const v4f*)(x + (unsigned)((gy << 7) + gx) * C + c4);
            *(v4f*)(&lds[row][col][c4]) = v;
        }
        __syncthreads();

        const int* lst = list + (size_t)b * CAP;
        for (int i = wave; i < n; i += 4) {
            cell_compute_store(rois, out, lst[i],
                               &lds[0][0][0], &lds[1][0][0],
                               C, colbase, c4, true, x);
        }
    } else {
        // Overflow drain (expected empty).
        const int n = *ocnt;
        for (int i = (blockIdx.x - NB) * 4 + wave; i < n; i += DRAIN_BLOCKS * 4) {
            cell_compute_store(rois, out, olist[i],
                               nullptr, nullptr, C, 0, c4, false, x);
        }
    }
}

// Fallback (ws too small): direct kernel over pairs.
__global__ __launch_bounds__(256) void roi_pool_plain(
    const float* __restrict__ x, const float* __restrict__ rois,
    float* __restrict__ out)
{
    const int wave = threadIdx.x >> 6;
    const int lane = threadIdx.x & 63;
    const int pr = blockIdx.x * 4 + wave;
    if (pr >= NPAIR) return;
    const int c4 = lane * 4;
#pragma unroll
    for (int ix = 0; ix < PW; ++ix)
        cell_compute_store(rois, out, (pr << 3) | ix,
                           nullptr, nullptr, C, 0, c4, false, x);
}

extern "C" void kernel_launch(void* const* d_in, const int* in_sizes, int n_in,
                              void* d_out, int out_size, void* d_ws, size_t ws_size,
                              hipStream_t stream)
{
    const float* x    = (const float*)d_in[0];
    const float* rois = (const float*)d_in[1];
    float* out = (float*)d_out;

    if (ws_size >= WS_INTS * sizeof(int)) {
        int* gcnt  = (int*)d_ws;
        int* ocnt  = gcnt + (size_t)NB * CS;
        int* list  = ocnt + CS;
        int* olist = list + (size_t)NB * CAP;
        zero_counts<<<32, 256, 0, stream>>>(gcnt);
        bin_cells<<<PAIR_BLOCKS, 256, 0, stream>>>(rois, gcnt, ocnt, list, olist);
        roi_pool_bucket<<<POOL_BLOCKS, 256, 0, stream>>>(x, rois, out, gcnt, list, ocnt, olist);
    } else {
        roi_pool_plain<<<(NPAIR + 3) / 4, 256, 0, stream>>>(x, rois, out);
    }
}

// Round 16
// 61.885 us; speedup vs baseline: 1.4561x; 1.4561x over previous
//
#include <hip/hip_runtime.h>

// RoiPooling (crop_and_resize, bilinear): x (1,128,128,256) f32 NHWC,
// rois (4000,4) f32 [y1,x1,y2,x2] in [0,1] -> out (4000,7,7,256) f32.
//
// R16: R14 + contiguous per-wave chunks in the pool.
// R14's loop (i += GROUPS*4) made each wave's consecutive pairs 1024 apart
// in the sorted list -> every iteration a fresh 2-row window -> zero L1
// temporal reuse, L2 64B-request-rate wall (~16 TB/s). Now wave w owns
// pairs [w*4, w*4+4) contiguous: 4 adjacent sorted pairs share the same
// ~2-row window -> L1 hits, fewer L2 requests. Sort chain unchanged (R14
// atomic-free 3-kernel: hist private counts, 1-block prefix+bases, scatter).

typedef float v4f __attribute__((ext_vector_type(4)));

constexpr int H = 128, W = 128, C = 256;
constexpr int PH = 7, PW = 7;
constexpr int NROI = 4000;
constexpr int NPAIR = NROI * PH;                 // 28000
constexpr int RBUCK = 128;                       // one bucket per y0 row
constexpr int PAIR_BLOCKS = (NPAIR + 255) / 256; // 110
constexpr int NXCD = 8;
constexpr int M = NPAIR / NXCD;                  // 3500 pairs per XCD
constexpr int PPW = 4;                           // pairs per wave (contiguous)
constexpr int WAVES_PER_XCD = (M + PPW - 1) / PPW;        // 875
constexpr int GROUPS = (WAVES_PER_XCD + 3) / 4;           // 219 blocks per XCD
constexpr int P2_BLOCKS = NXCD * GROUPS;                  // 1752
// ws: blockcnt[110][128] | base[110][128] | list[28000]
constexpr size_t WS_INTS = (size_t)PAIR_BLOCKS * RBUCK * 2 + NPAIR;

__device__ __forceinline__ int pair_ybucket(const float* __restrict__ rois, int pr) {
    const int r  = pr / PH;
    const int iy = pr - r * PH;
    const float y1 = rois[r * 4 + 0];
    const float y2 = rois[r * 4 + 2];
    const float ys = y1 * (float)(H - 1) + (float)iy * ((y2 - y1) * (float)(H - 1) / (float)(PH - 1));
    int y0 = (int)floorf(ys);
    return min(max(y0, 0), H - 1);
}

__global__ __launch_bounds__(256) void hist_pairs(const float* __restrict__ rois,
                                                  int* __restrict__ blockcnt)
{
    __shared__ int lh[RBUCK];
    if (threadIdx.x < RBUCK) lh[threadIdx.x] = 0;
    __syncthreads();
    const int pr = blockIdx.x * 256 + threadIdx.x;
    if (pr < NPAIR) atomicAdd(&lh[pair_ybucket(rois, pr)], 1);
    __syncthreads();
    if (threadIdx.x < RBUCK)
        blockcnt[blockIdx.x * RBUCK + threadIdx.x] = lh[threadIdx.x];
}

__global__ __launch_bounds__(128) void prefix_base(const int* __restrict__ blockcnt,
                                                   int* __restrict__ base)
{
    __shared__ int s[RBUCK];
    const int t = threadIdx.x;
    int tot = 0;
    for (int blk = 0; blk < PAIR_BLOCKS; ++blk) tot += blockcnt[blk * RBUCK + t];
    s[t] = tot;
    __syncthreads();
    for (int off = 1; off < RBUCK; off <<= 1) {
        const int v = (t >= off) ? s[t - off] : 0;
        __syncthreads();
        s[t] += v;
        __syncthreads();
    }
    int run = (t == 0) ? 0 : s[t - 1];           // exclusive global prefix
    for (int blk = 0; blk < PAIR_BLOCKS; ++blk) {
        const int v = blockcnt[blk * RBUCK + t];
        base[blk * RBUCK + t] = run;
        run += v;
    }
}

__global__ __launch_bounds__(256) void scatter_pairs(const float* __restrict__ rois,
                                                     const int* __restrict__ base,
                                                     int* __restrict__ list)
{
    __shared__ int lcnt[RBUCK];
    __shared__ int gbase[RBUCK];
    if (threadIdx.x < RBUCK) {
        lcnt[threadIdx.x] = 0;
        gbase[threadIdx.x] = base[blockIdx.x * RBUCK + threadIdx.x];
    }
    __syncthreads();
    const int pr = blockIdx.x * 256 + threadIdx.x;
    if (pr < NPAIR) {
        const int b = pair_ybucket(rois, pr);
        const int rank = atomicAdd(&lcnt[b], 1);
        const int r  = pr / PH;
        const int iy = pr - r * PH;
        list[gbase[b] + rank] = (r << 3) | iy;   // packed
    }
}

__global__ __launch_bounds__(256) void roi_pool_pairs(
    const float* __restrict__ x, const float* __restrict__ rois,
    float* __restrict__ out, const int* __restrict__ list)
{
    const int xcd = blockIdx.x & (NXCD - 1);   // heuristic: == XCD id
    const int grp = blockIdx.x >> 3;
    const int wave = threadIdx.x >> 6;
    const int lane = threadIdx.x & 63;
    const unsigned c4 = (unsigned)lane * 4u;

    // Contiguous chunk: wave w (of this XCD) owns pairs [w*PPW, w*PPW+PPW).
    const int w = grp * 4 + wave;
    const int i0 = w * PPW;
    if (i0 >= M) return;
    const int i1 = min(i0 + PPW, M);
    const int base = xcd * M;

    for (int i = i0; i < i1; ++i) {
        const int packed = list[base + i];
        const int r  = packed >> 3;
        const int iy = packed & 7;

        const float y1 = rois[r * 4 + 0];
        const float x1 = rois[r * 4 + 1];
        const float y2 = rois[r * 4 + 2];
        const float x2 = rois[r * 4 + 3];

        // Match reference order exactly.
        const float ys = y1 * (float)(H - 1) + (float)iy * ((y2 - y1) * (float)(H - 1) / (float)(PH - 1));
        const float y0f = floorf(ys);
        const float wy = ys - y0f;
        int y0  = (int)y0f; y0  = min(max(y0, 0), H - 1);
        int y1i = min(y0 + 1, H - 1);
        const bool vy = (ys >= 0.0f) & (ys <= (float)(H - 1));

        const float* __restrict__ row0 = x + (unsigned)y0  * (W * C);
        const float* __restrict__ row1 = x + (unsigned)y1i * (W * C);
        float* __restrict__ obase = out + (unsigned)(r * 49 + iy * 7) * C;

#pragma unroll
        for (int ix = 0; ix < PW; ++ix) {
            const float xs = x1 * (float)(W - 1) + (float)ix * ((x2 - x1) * (float)(W - 1) / (float)(PW - 1));
            const float x0f = floorf(xs);
            const float wx = xs - x0f;
            int x0  = (int)x0f; x0  = min(max(x0, 0), W - 1);
            int x1c = min(x0 + 1, W - 1);
            const bool v = vy & (xs >= 0.0f) & (xs <= (float)(W - 1));

            const v4f a = *(const v4f*)(row0 + (unsigned)x0  * C + c4);
            const v4f b = *(const v4f*)(row0 + (unsigned)x1c * C + c4);
            const v4f c = *(const v4f*)(row1 + (unsigned)x0  * C + c4);
            const v4f d = *(const v4f*)(row1 + (unsigned)x1c * C + c4);

            const v4f top = a * (1.0f - wx) + b * wx;
            const v4f bot = c * (1.0f - wx) + d * wx;
            v4f res = top * (1.0f - wy) + bot * wy;
            if (!v) res = (v4f)0.0f;
            __builtin_nontemporal_store(res, (v4f*)(obase + (unsigned)ix * C + c4));
        }
    }
}

// Fallback (ws too small): direct kernel over pairs.
__global__ __launch_bounds__(256) void roi_pool_plain(
    const float* __restrict__ x, const float* __restrict__ rois,
    float* __restrict__ out)
{
    const int wave = threadIdx.x >> 6;
    const int lane = threadIdx.x & 63;
    const int pr = blockIdx.x * 4 + wave;
    if (pr >= NPAIR) return;
    const int r  = pr / PH;
    const int iy = pr - r * PH;
    const unsigned c4 = (unsigned)lane * 4u;

    const float y1 = rois[r * 4 + 0];
    const float x1 = rois[r * 4 + 1];
    const float y2 = rois[r * 4 + 2];
    const float x2 = rois[r * 4 + 3];

    const float ys = y1 * (float)(H - 1) + (float)iy * ((y2 - y1) * (float)(H - 1) / (float)(PH - 1));
    const float y0f = floorf(ys);
    const float wy = ys - y0f;
    int y0  = (int)y0f; y0  = min(max(y0, 0), H - 1);
    int y1i = min(y0 + 1, H - 1);
    const bool vy = (ys >= 0.0f) & (ys <= (float)(H - 1));

    const float* __restrict__ row0 = x + (unsigned)y0  * (W * C);
    const float* __restrict__ row1 = x + (unsigned)y1i * (W * C);
    float* __restrict__ obase = out + (unsigned)(r * 49 + iy * 7) * C;

#pragma unroll
    for (int ix = 0; ix < PW; ++ix) {
        const float xs = x1 * (float)(W - 1) + (float)ix * ((x2 - x1) * (float)(W - 1) / (float)(PW - 1));
        const float x0f = floorf(xs);
        const float wx = xs - x0f;
        int x0  = (int)x0f; x0  = min(max(x0, 0), W - 1);
        int x1c = min(x0 + 1, W - 1);
        const bool v = vy & (xs >= 0.0f) & (xs <= (float)(W - 1));

        const v4f a = *(const v4f*)(row0 + (unsigned)x0  * C + c4);
        const v4f b = *(const v4f*)(row0 + (unsigned)x1c * C + c4);
        const v4f c = *(const v4f*)(row1 + (unsigned)x0  * C + c4);
        const v4f d = *(const v4f*)(row1 + (unsigned)x1c * C + c4);

        const v4f top = a * (1.0f - wx) + b * wx;
        const v4f bot = c * (1.0f - wx) + d * wx;
        v4f res = top * (1.0f - wy) + bot * wy;
        if (!v) res = (v4f)0.0f;
        __builtin_nontemporal_store(res, (v4f*)(obase + (unsigned)ix * C + c4));
    }
}

extern "C" void kernel_launch(void* const* d_in, const int* in_sizes, int n_in,
                              void* d_out, int out_size, void* d_ws, size_t ws_size,
                              hipStream_t stream)
{
    const float* x    = (const float*)d_in[0];
    const float* rois = (const float*)d_in[1];
    float* out = (float*)d_out;

    if (ws_size >= WS_INTS * sizeof(int)) {
        int* blockcnt = (int*)d_ws;
        int* base     = blockcnt + (size_t)PAIR_BLOCKS * RBUCK;
        int* list     = base + (size_t)PAIR_BLOCKS * RBUCK;
        hist_pairs<<<PAIR_BLOCKS, 256, 0, stream>>>(rois, blockcnt);
        prefix_base<<<1, 128, 0, stream>>>(blockcnt, base);
        scatter_pairs<<<PAIR_BLOCKS, 256, 0, stream>>>(rois, base, list);
        roi_pool_pairs<<<P2_BLOCKS, 256, 0, stream>>>(x, rois, out, list);
    } else {
        roi_pool_plain<<<(NPAIR + 3) / 4, 256, 0, stream>>>(x, rois, out);
    }
}